// Round 6
// baseline (2069.196 us; speedup 1.0000x reference)
//
#include <hip/hip_runtime.h>
#include <hip/hip_bf16.h>
#include <stdint.h>

#define N_LEVELS   16
#define LOG2_T     19
#define TABLE_SIZE (1u << LOG2_T)
#define PRIME_Y    2654435761u
#define PRIME_Z    805459861u

typedef float v2f __attribute__((ext_vector_type(2)));

// ============================ Kernel A: encode ============================
// Thread = (point, level-pair): 8 threads/point, 2 levels/thread.
// All 16 gathers issued before any consumption -> ~16 outstanding vmem
// loads per lane (vs 8 in round 5) => 2x memory-level parallelism at the
// same 8-waves/SIMD occupancy (target <=64 VGPR). Encode is latency-bound
// (round 5: occ 84%, VALU 5.5%, HBM 43%, implied ~600cyc avg latency).
__global__ __launch_bounds__(256, 8)
void encode_kernel(const float* __restrict__ x,           // [N,3]
                   const float* __restrict__ tables,      // [16, T, 2]
                   const float* __restrict__ resolutions, // [16]
                   float* __restrict__ a_ws,              // [32, N]
                   int n)
{
    const int tid = blockIdx.x * blockDim.x + threadIdx.x;
    int p = tid >> 3;
    const int lp = tid & 7;                  // handles levels 2lp, 2lp+1
    if (p >= n) p = n - 1;                   // benign duplicate work

    const float x0 = x[3 * p + 0] * 0.5f + 0.5f;
    const float x1 = x[3 * p + 1] * 0.5f + 0.5f;
    const float x2 = x[3 * p + 2] * 0.5f + 0.5f;

    float wxs[2], wys[2], wzs[2];
    float2 fv[16];

    // ---- issue phase: 16 independent gathers, no consumption ----
    #pragma unroll
    for (int s = 0; s < 2; ++s) {
        const int l = 2 * lp + s;
        const float res = resolutions[l];
        const float px = x0 * res, py = x1 * res, pz = x2 * res;
        const float fx = floorf(px), fy = floorf(py), fz = floorf(pz);
        wxs[s] = px - fx;  wys[s] = py - fy;  wzs[s] = pz - fz;
        const uint32_t cx = (uint32_t)fx;
        const uint32_t cy = (uint32_t)fy;
        const uint32_t cz = (uint32_t)fz;

        const uint32_t hx0 = cx,           hx1 = cx + 1u;
        const uint32_t hy0 = cy * PRIME_Y, hy1 = hy0 + PRIME_Y;
        const uint32_t hz0 = cz * PRIME_Z, hz1 = hz0 + PRIME_Z;

        const float* __restrict__ tab = tables + (size_t)l * (size_t)TABLE_SIZE * 2u;

        #pragma unroll
        for (int c = 0; c < 8; ++c) {
            const uint32_t h = ((c & 1) ? hx1 : hx0) ^
                               ((c & 2) ? hy1 : hy0) ^
                               ((c & 4) ? hz1 : hz0);
            const uint32_t idx = h & (TABLE_SIZE - 1u);
            fv[8 * s + c] = *(const float2*)(tab + 2u * idx);
        }
    }

    // ---- consume phase ----
    #pragma unroll
    for (int s = 0; s < 2; ++s) {
        const int l = 2 * lp + s;
        const float wx = wxs[s], wy = wys[s], wz = wzs[s];
        const float wx0 = 1.0f - wx, wy0 = 1.0f - wy, wz0 = 1.0f - wz;
        float f0 = 0.0f, f1 = 0.0f;
        #pragma unroll
        for (int c = 0; c < 8; ++c) {
            const float wgt = ((c & 1) ? wx : wx0) *
                              ((c & 2) ? wy : wy0) *
                              ((c & 4) ? wz : wz0);
            f0 = fmaf(wgt, fv[8 * s + c].x, f0);
            f1 = fmaf(wgt, fv[8 * s + c].y, f1);
        }
        a_ws[(size_t)(2 * l + 0) * n + p] = f0;
        a_ws[(size_t)(2 * l + 1) * n + p] = f1;
    }
}

// ============================ Kernel B: MLP ============================
// One thread per point; SGPR weights + v_pk_fma_f32 (validated round 5).
__global__ __launch_bounds__(256, 3)
void mlp_kernel(const float* __restrict__ a_ws,   // [32, N]
                const float* __restrict__ W1,     // [32,64]
                const float* __restrict__ b1,     // [64]
                const float* __restrict__ W2,     // [64,64]
                const float* __restrict__ b2,     // [64]
                const float* __restrict__ W3,     // [64,1]
                const float* __restrict__ b3,     // [1]
                float* __restrict__ out,          // [N]
                int n)
{
    const int i  = blockIdx.x * blockDim.x + threadIdx.x;
    const int ip = (i < n) ? i : (n - 1);

    float a[32];
    #pragma unroll
    for (int k = 0; k < 32; ++k)
        a[k] = a_ws[(size_t)k * n + ip];

    const v2f zero = {0.0f, 0.0f};

    v2f H1[32];
    #pragma unroll
    for (int j2 = 0; j2 < 32; ++j2) {
        const float2 b = *(const float2*)&b1[2 * j2];
        H1[j2] = (v2f){b.x, b.y};
    }
    #pragma unroll
    for (int k = 0; k < 32; ++k) {
        const float ak = a[k];
        const v2f vA = {ak, ak};
        #pragma unroll
        for (int j4 = 0; j4 < 16; ++j4) {
            const float4 w = *(const float4*)&W1[k * 64 + j4 * 4];
            H1[j4 * 2 + 0] = __builtin_elementwise_fma(vA, (v2f){w.x, w.y}, H1[j4 * 2 + 0]);
            H1[j4 * 2 + 1] = __builtin_elementwise_fma(vA, (v2f){w.z, w.w}, H1[j4 * 2 + 1]);
        }
    }
    #pragma unroll
    for (int j2 = 0; j2 < 32; ++j2)
        H1[j2] = __builtin_elementwise_max(H1[j2], zero);

    v2f acc = zero;
    #pragma unroll
    for (int half = 0; half < 2; ++half) {
        v2f H2[16];
        #pragma unroll
        for (int j2 = 0; j2 < 16; ++j2) {
            const float2 b = *(const float2*)&b2[half * 32 + 2 * j2];
            H2[j2] = (v2f){b.x, b.y};
        }
        #pragma unroll
        for (int k2 = 0; k2 < 32; ++k2) {
            const v2f hp = H1[k2];
            #pragma unroll
            for (int kk = 0; kk < 2; ++kk) {
                const float hk = kk ? hp.y : hp.x;
                const v2f vH = {hk, hk};
                const int k = 2 * k2 + kk;
                #pragma unroll
                for (int j4 = 0; j4 < 8; ++j4) {
                    const float4 w = *(const float4*)&W2[k * 64 + half * 32 + j4 * 4];
                    H2[j4 * 2 + 0] = __builtin_elementwise_fma(vH, (v2f){w.x, w.y}, H2[j4 * 2 + 0]);
                    H2[j4 * 2 + 1] = __builtin_elementwise_fma(vH, (v2f){w.z, w.w}, H2[j4 * 2 + 1]);
                }
            }
        }
        #pragma unroll
        for (int j2 = 0; j2 < 16; ++j2) {
            const float2 w3 = *(const float2*)&W3[half * 32 + 2 * j2];
            acc = __builtin_elementwise_fma(__builtin_elementwise_max(H2[j2], zero),
                                            (v2f){w3.x, w3.y}, acc);
        }
    }

    out[ip] = acc.x + acc.y + b3[0];
}

// ==================== Fallback: round-4 fused kernel ====================
__global__ __launch_bounds__(256, 4)
void hashgrid_mlp_fused(const float* __restrict__ x,
                        const float* __restrict__ tables,
                        const float* __restrict__ resolutions,
                        const float* __restrict__ W1,
                        const float* __restrict__ b1,
                        const float* __restrict__ W2,
                        const float* __restrict__ b2,
                        const float* __restrict__ W3,
                        const float* __restrict__ b3,
                        float* __restrict__ out,
                        int n)
{
    const int i  = blockIdx.x * blockDim.x + threadIdx.x;
    const int ip = (i < n) ? i : (n - 1);

    const float x0 = x[3 * ip + 0] * 0.5f + 0.5f;
    const float x1 = x[3 * ip + 1] * 0.5f + 0.5f;
    const float x2 = x[3 * ip + 2] * 0.5f + 0.5f;

    float h1[64];
    #pragma unroll
    for (int j = 0; j < 64; ++j) h1[j] = b1[j];

    #pragma unroll
    for (int l = 0; l < N_LEVELS; ++l) {
        const float res = resolutions[l];
        const float px = x0 * res, py = x1 * res, pz = x2 * res;
        const float fx = floorf(px), fy = floorf(py), fz = floorf(pz);
        const float wx = px - fx, wy = py - fy, wz = pz - fz;
        const uint32_t cx = (uint32_t)fx;
        const uint32_t cy = (uint32_t)fy;
        const uint32_t cz = (uint32_t)fz;
        const uint32_t hx0 = cx,           hx1 = cx + 1u;
        const uint32_t hy0 = cy * PRIME_Y, hy1 = hy0 + PRIME_Y;
        const uint32_t hz0 = cz * PRIME_Z, hz1 = hz0 + PRIME_Z;
        const float wx0 = 1.0f - wx, wy0 = 1.0f - wy, wz0 = 1.0f - wz;
        const float* __restrict__ tab = tables + (size_t)l * (size_t)TABLE_SIZE * 2u;

        float f0 = 0.0f, f1 = 0.0f;
        #pragma unroll
        for (int c = 0; c < 8; ++c) {
            const uint32_t h = ((c & 1) ? hx1 : hx0) ^
                               ((c & 2) ? hy1 : hy0) ^
                               ((c & 4) ? hz1 : hz0);
            const uint32_t idx = h & (TABLE_SIZE - 1u);
            const float2 fv = *(const float2*)(tab + 2u * idx);
            const float wgt = ((c & 1) ? wx : wx0) *
                              ((c & 2) ? wy : wy0) *
                              ((c & 4) ? wz : wz0);
            f0 = fmaf(wgt, fv.x, f0);
            f1 = fmaf(wgt, fv.y, f1);
        }
        const float* __restrict__ w1a = W1 + (2 * l + 0) * 64;
        const float* __restrict__ w1b = W1 + (2 * l + 1) * 64;
        #pragma unroll
        for (int j = 0; j < 64; ++j)
            h1[j] = fmaf(f1, w1b[j], fmaf(f0, w1a[j], h1[j]));
    }

    #pragma unroll
    for (int j = 0; j < 64; ++j) h1[j] = fmaxf(h1[j], 0.0f);

    float accum = b3[0];
    #pragma unroll
    for (int half = 0; half < 2; ++half) {
        float h2[32];
        #pragma unroll
        for (int j = 0; j < 32; ++j) h2[j] = b2[half * 32 + j];
        #pragma unroll
        for (int k = 0; k < 64; ++k) {
            const float hk = h1[k];
            const float* __restrict__ w2row = W2 + k * 64 + half * 32;
            #pragma unroll
            for (int j = 0; j < 32; ++j)
                h2[j] = fmaf(hk, w2row[j], h2[j]);
        }
        #pragma unroll
        for (int j = 0; j < 32; ++j)
            accum = fmaf(fmaxf(h2[j], 0.0f), W3[half * 32 + j], accum);
    }
    out[ip] = accum;
}

extern "C" void kernel_launch(void* const* d_in, const int* in_sizes, int n_in,
                              void* d_out, int out_size, void* d_ws, size_t ws_size,
                              hipStream_t stream) {
    const float* x           = (const float*)d_in[0];
    const float* tables      = (const float*)d_in[1];
    const float* resolutions = (const float*)d_in[2];
    const float* W1          = (const float*)d_in[3];
    const float* b1          = (const float*)d_in[4];
    const float* W2          = (const float*)d_in[5];
    const float* b2          = (const float*)d_in[6];
    const float* W3          = (const float*)d_in[7];
    const float* b3          = (const float*)d_in[8];
    float* out               = (float*)d_out;

    const int n = out_size;  // 2,000,000
    const int block = 256;
    const size_t ws_needed = (size_t)n * 32u * sizeof(float);

    if (ws_size >= ws_needed) {
        float* a_ws = (float*)d_ws;
        const long long nthreads_enc = (long long)n * 8;
        const int grid_enc = (int)((nthreads_enc + block - 1) / block);
        const int grid_mlp = (n + block - 1) / block;
        encode_kernel<<<grid_enc, block, 0, stream>>>(x, tables, resolutions, a_ws, n);
        mlp_kernel<<<grid_mlp, block, 0, stream>>>(a_ws, W1, b1, W2, b2, W3, b3, out, n);
    } else {
        const int grid = (n + block - 1) / block;
        hashgrid_mlp_fused<<<grid, block, 0, stream>>>(
            x, tables, resolutions, W1, b1, W2, b2, W3, b3, out, n);
    }
}

// Round 7
// 1222.644 us; speedup vs baseline: 1.6924x; 1.6924x over previous
//
#include <hip/hip_runtime.h>
#include <hip/hip_bf16.h>
#include <stdint.h>

#define N_LEVELS   16
#define LOG2_T     19
#define TABLE_SIZE (1u << LOG2_T)
#define PRIME_Y    2654435761u
#define PRIME_Z    805459861u

typedef float v2f __attribute__((ext_vector_type(2)));

// ============================ Kernel A: encode ============================
// LEVEL-MAJOR: blockIdx.y = level (slow-varying -> all level-0 blocks
// dispatch first). At any instant the GPU works on ~1 level, whose 4 MB
// table fits exactly in each XCD's 4 MB L2 -> gathers become L2 hits.
// Round-5/6 evidence: encode dur == FETCH bytes / ~3.6 TB/s (random-line
// HBM ceiling); the lever is FETCH reduction, not MLR.
__global__ __launch_bounds__(256, 8)
void encode_kernel(const float* __restrict__ x,           // [N,3]
                   const float* __restrict__ tables,      // [16, T, 2]
                   const float* __restrict__ resolutions, // [16]
                   float* __restrict__ a_ws,              // [32, N]
                   int n)
{
    const int l = blockIdx.y;                       // level 0..15
    int p = blockIdx.x * blockDim.x + threadIdx.x;  // point
    if (p >= n) p = n - 1;                          // uniform CF; dup benign

    const float x0 = x[3 * p + 0] * 0.5f + 0.5f;
    const float x1 = x[3 * p + 1] * 0.5f + 0.5f;
    const float x2 = x[3 * p + 2] * 0.5f + 0.5f;

    const float res = resolutions[l];
    const float px = x0 * res, py = x1 * res, pz = x2 * res;
    const float fx = floorf(px), fy = floorf(py), fz = floorf(pz);
    const float wx = px - fx, wy = py - fy, wz = pz - fz;
    const uint32_t cx = (uint32_t)fx;
    const uint32_t cy = (uint32_t)fy;
    const uint32_t cz = (uint32_t)fz;

    const uint32_t hx0 = cx,           hx1 = cx + 1u;
    const uint32_t hy0 = cy * PRIME_Y, hy1 = hy0 + PRIME_Y;
    const uint32_t hz0 = cz * PRIME_Z, hz1 = hz0 + PRIME_Z;

    const float wx0 = 1.0f - wx, wy0 = 1.0f - wy, wz0 = 1.0f - wz;

    const float* __restrict__ tab = tables + (size_t)l * (size_t)TABLE_SIZE * 2u;

    // issue all 8 gathers before consumption
    float2 fv[8];
    #pragma unroll
    for (int c = 0; c < 8; ++c) {
        const uint32_t h = ((c & 1) ? hx1 : hx0) ^
                           ((c & 2) ? hy1 : hy0) ^
                           ((c & 4) ? hz1 : hz0);
        const uint32_t idx = h & (TABLE_SIZE - 1u);
        fv[c] = *(const float2*)(tab + 2u * idx);
    }

    float f0 = 0.0f, f1 = 0.0f;
    #pragma unroll
    for (int c = 0; c < 8; ++c) {
        const float wgt = ((c & 1) ? wx : wx0) *
                          ((c & 2) ? wy : wy0) *
                          ((c & 4) ? wz : wz0);
        f0 = fmaf(wgt, fv[c].x, f0);
        f1 = fmaf(wgt, fv[c].y, f1);
    }
    a_ws[(size_t)(2 * l + 0) * n + p] = f0;
    a_ws[(size_t)(2 * l + 1) * n + p] = f1;
}

// ============================ Kernel B: MLP ============================
// One thread per point; SGPR weights + v_pk_fma_f32 (validated rounds 4/5).
__global__ __launch_bounds__(256, 3)
void mlp_kernel(const float* __restrict__ a_ws,   // [32, N]
                const float* __restrict__ W1,     // [32,64]
                const float* __restrict__ b1,     // [64]
                const float* __restrict__ W2,     // [64,64]
                const float* __restrict__ b2,     // [64]
                const float* __restrict__ W3,     // [64,1]
                const float* __restrict__ b3,     // [1]
                float* __restrict__ out,          // [N]
                int n)
{
    const int i  = blockIdx.x * blockDim.x + threadIdx.x;
    const int ip = (i < n) ? i : (n - 1);

    float a[32];
    #pragma unroll
    for (int k = 0; k < 32; ++k)
        a[k] = a_ws[(size_t)k * n + ip];

    const v2f zero = {0.0f, 0.0f};

    v2f H1[32];
    #pragma unroll
    for (int j2 = 0; j2 < 32; ++j2) {
        const float2 b = *(const float2*)&b1[2 * j2];
        H1[j2] = (v2f){b.x, b.y};
    }
    #pragma unroll
    for (int k = 0; k < 32; ++k) {
        const float ak = a[k];
        const v2f vA = {ak, ak};
        #pragma unroll
        for (int j4 = 0; j4 < 16; ++j4) {
            const float4 w = *(const float4*)&W1[k * 64 + j4 * 4];
            H1[j4 * 2 + 0] = __builtin_elementwise_fma(vA, (v2f){w.x, w.y}, H1[j4 * 2 + 0]);
            H1[j4 * 2 + 1] = __builtin_elementwise_fma(vA, (v2f){w.z, w.w}, H1[j4 * 2 + 1]);
        }
    }
    #pragma unroll
    for (int j2 = 0; j2 < 32; ++j2)
        H1[j2] = __builtin_elementwise_max(H1[j2], zero);

    v2f acc = zero;
    #pragma unroll
    for (int half = 0; half < 2; ++half) {
        v2f H2[16];
        #pragma unroll
        for (int j2 = 0; j2 < 16; ++j2) {
            const float2 b = *(const float2*)&b2[half * 32 + 2 * j2];
            H2[j2] = (v2f){b.x, b.y};
        }
        #pragma unroll
        for (int k2 = 0; k2 < 32; ++k2) {
            const v2f hp = H1[k2];
            #pragma unroll
            for (int kk = 0; kk < 2; ++kk) {
                const float hk = kk ? hp.y : hp.x;
                const v2f vH = {hk, hk};
                const int k = 2 * k2 + kk;
                #pragma unroll
                for (int j4 = 0; j4 < 8; ++j4) {
                    const float4 w = *(const float4*)&W2[k * 64 + half * 32 + j4 * 4];
                    H2[j4 * 2 + 0] = __builtin_elementwise_fma(vH, (v2f){w.x, w.y}, H2[j4 * 2 + 0]);
                    H2[j4 * 2 + 1] = __builtin_elementwise_fma(vH, (v2f){w.z, w.w}, H2[j4 * 2 + 1]);
                }
            }
        }
        #pragma unroll
        for (int j2 = 0; j2 < 16; ++j2) {
            const float2 w3 = *(const float2*)&W3[half * 32 + 2 * j2];
            acc = __builtin_elementwise_fma(__builtin_elementwise_max(H2[j2], zero),
                                            (v2f){w3.x, w3.y}, acc);
        }
    }

    out[ip] = acc.x + acc.y + b3[0];
}

// ==================== Fallback: round-4 fused kernel ====================
__global__ __launch_bounds__(256, 4)
void hashgrid_mlp_fused(const float* __restrict__ x,
                        const float* __restrict__ tables,
                        const float* __restrict__ resolutions,
                        const float* __restrict__ W1,
                        const float* __restrict__ b1,
                        const float* __restrict__ W2,
                        const float* __restrict__ b2,
                        const float* __restrict__ W3,
                        const float* __restrict__ b3,
                        float* __restrict__ out,
                        int n)
{
    const int i  = blockIdx.x * blockDim.x + threadIdx.x;
    const int ip = (i < n) ? i : (n - 1);

    const float x0 = x[3 * ip + 0] * 0.5f + 0.5f;
    const float x1 = x[3 * ip + 1] * 0.5f + 0.5f;
    const float x2 = x[3 * ip + 2] * 0.5f + 0.5f;

    float h1[64];
    #pragma unroll
    for (int j = 0; j < 64; ++j) h1[j] = b1[j];

    #pragma unroll
    for (int l = 0; l < N_LEVELS; ++l) {
        const float res = resolutions[l];
        const float px = x0 * res, py = x1 * res, pz = x2 * res;
        const float fx = floorf(px), fy = floorf(py), fz = floorf(pz);
        const float wx = px - fx, wy = py - fy, wz = pz - fz;
        const uint32_t cx = (uint32_t)fx;
        const uint32_t cy = (uint32_t)fy;
        const uint32_t cz = (uint32_t)fz;
        const uint32_t hx0 = cx,           hx1 = cx + 1u;
        const uint32_t hy0 = cy * PRIME_Y, hy1 = hy0 + PRIME_Y;
        const uint32_t hz0 = cz * PRIME_Z, hz1 = hz0 + PRIME_Z;
        const float wx0 = 1.0f - wx, wy0 = 1.0f - wy, wz0 = 1.0f - wz;
        const float* __restrict__ tab = tables + (size_t)l * (size_t)TABLE_SIZE * 2u;

        float f0 = 0.0f, f1 = 0.0f;
        #pragma unroll
        for (int c = 0; c < 8; ++c) {
            const uint32_t h = ((c & 1) ? hx1 : hx0) ^
                               ((c & 2) ? hy1 : hy0) ^
                               ((c & 4) ? hz1 : hz0);
            const uint32_t idx = h & (TABLE_SIZE - 1u);
            const float2 fv = *(const float2*)(tab + 2u * idx);
            const float wgt = ((c & 1) ? wx : wx0) *
                              ((c & 2) ? wy : wy0) *
                              ((c & 4) ? wz : wz0);
            f0 = fmaf(wgt, fv.x, f0);
            f1 = fmaf(wgt, fv.y, f1);
        }
        const float* __restrict__ w1a = W1 + (2 * l + 0) * 64;
        const float* __restrict__ w1b = W1 + (2 * l + 1) * 64;
        #pragma unroll
        for (int j = 0; j < 64; ++j)
            h1[j] = fmaf(f1, w1b[j], fmaf(f0, w1a[j], h1[j]));
    }

    #pragma unroll
    for (int j = 0; j < 64; ++j) h1[j] = fmaxf(h1[j], 0.0f);

    float accum = b3[0];
    #pragma unroll
    for (int half = 0; half < 2; ++half) {
        float h2[32];
        #pragma unroll
        for (int j = 0; j < 32; ++j) h2[j] = b2[half * 32 + j];
        #pragma unroll
        for (int k = 0; k < 64; ++k) {
            const float hk = h1[k];
            const float* __restrict__ w2row = W2 + k * 64 + half * 32;
            #pragma unroll
            for (int j = 0; j < 32; ++j)
                h2[j] = fmaf(hk, w2row[j], h2[j]);
        }
        #pragma unroll
        for (int j = 0; j < 32; ++j)
            accum = fmaf(fmaxf(h2[j], 0.0f), W3[half * 32 + j], accum);
    }
    out[ip] = accum;
}

extern "C" void kernel_launch(void* const* d_in, const int* in_sizes, int n_in,
                              void* d_out, int out_size, void* d_ws, size_t ws_size,
                              hipStream_t stream) {
    const float* x           = (const float*)d_in[0];
    const float* tables      = (const float*)d_in[1];
    const float* resolutions = (const float*)d_in[2];
    const float* W1          = (const float*)d_in[3];
    const float* b1          = (const float*)d_in[4];
    const float* W2          = (const float*)d_in[5];
    const float* b2          = (const float*)d_in[6];
    const float* W3          = (const float*)d_in[7];
    const float* b3          = (const float*)d_in[8];
    float* out               = (float*)d_out;

    const int n = out_size;  // 2,000,000
    const int block = 256;
    const size_t ws_needed = (size_t)n * 32u * sizeof(float);

    if (ws_size >= ws_needed) {
        float* a_ws = (float*)d_ws;
        const int grid_x = (n + block - 1) / block;
        dim3 grid_enc(grid_x, N_LEVELS);   // y = level, slow-varying
        encode_kernel<<<grid_enc, block, 0, stream>>>(x, tables, resolutions, a_ws, n);
        mlp_kernel<<<grid_x, block, 0, stream>>>(a_ws, W1, b1, W2, b2, W3, b3, out, n);
    } else {
        const int grid = (n + block - 1) / block;
        hashgrid_mlp_fused<<<grid, block, 0, stream>>>(
            x, tables, resolutions, W1, b1, W2, b2, W3, b3, out, n);
    }
}

// Round 8
// 1001.540 us; speedup vs baseline: 2.0660x; 1.2208x over previous
//
#include <hip/hip_runtime.h>
#include <hip/hip_bf16.h>
#include <stdint.h>

#define N_LEVELS   16
#define LOG2_T     19
#define TABLE_SIZE (1u << LOG2_T)
#define PRIME_Y    2654435761u
#define PRIME_Z    805459861u

typedef float v2f __attribute__((ext_vector_type(2)));

// ============================ Kernel A: encode ============================
// Level-major (round 7: tables L2-resident, FETCH 0.65 GB). Now bound by
// L2 request rate (~128 req/cyc aggregate -> 833 us for 256M requests).
// New: x-corner PAIR MERGING. PRIME_x == 1, so corners (c, c|1) have
// idx_b = idx_a ^ 1 when cx is even -> both 8B entries sit in one aligned
// 16B chunk -> one float4 load serves both corners (-25% requests expected).
// Arithmetic (weights, fmaf order, indices) identical to round 7.
__global__ __launch_bounds__(256, 8)
void encode_kernel(const float* __restrict__ x,           // [N,3]
                   const float* __restrict__ tables,      // [16, T, 2]
                   const float* __restrict__ resolutions, // [16]
                   float* __restrict__ a_ws,              // [32, N]
                   int n)
{
    const int l = blockIdx.y;                       // level 0..15
    int p = blockIdx.x * blockDim.x + threadIdx.x;  // point
    if (p >= n) p = n - 1;                          // uniform CF; dup benign

    const float x0 = x[3 * p + 0] * 0.5f + 0.5f;
    const float x1 = x[3 * p + 1] * 0.5f + 0.5f;
    const float x2 = x[3 * p + 2] * 0.5f + 0.5f;

    const float res = resolutions[l];
    const float px = x0 * res, py = x1 * res, pz = x2 * res;
    const float fx = floorf(px), fy = floorf(py), fz = floorf(pz);
    const float wx = px - fx, wy = py - fy, wz = pz - fz;
    const uint32_t cx = (uint32_t)fx;
    const uint32_t cy = (uint32_t)fy;
    const uint32_t cz = (uint32_t)fz;

    const uint32_t hy0 = cy * PRIME_Y, hy1 = hy0 + PRIME_Y;
    const uint32_t hz0 = cz * PRIME_Z, hz1 = hz0 + PRIME_Z;

    const float wx0 = 1.0f - wx, wy0 = 1.0f - wy, wz0 = 1.0f - wz;

    const float* __restrict__ tab = tables + (size_t)l * (size_t)TABLE_SIZE * 2u;

    // pair p2 = corners (2*p2, 2*p2+1): same (y,z), x in {cx, cx+1}
    const uint32_t hyz[4] = { hy0 ^ hz0, hy1 ^ hz0, hy0 ^ hz1, hy1 ^ hz1 };

    // corner values: cva[p2] = x-bit 0 corner, cvb[p2] = x-bit 1 corner
    float2 cva[4], cvb[4];

    if ((cx & 1u) == 0u) {
        // even cx: idx_b = idx_a ^ 1 -> one float4 covers both corners
        #pragma unroll
        for (int q = 0; q < 4; ++q) {
            const uint32_t idx_a = (cx ^ hyz[q]) & (TABLE_SIZE - 1u);
            const uint32_t base  = idx_a & ~1u;
            const float4 f4 = *(const float4*)(tab + 2u * base);
            const bool hi = (idx_a & 1u) != 0u;   // idx_a in upper half?
            cva[q] = hi ? make_float2(f4.z, f4.w) : make_float2(f4.x, f4.y);
            cvb[q] = hi ? make_float2(f4.x, f4.y) : make_float2(f4.z, f4.w);
        }
    } else {
        // odd cx: two independent float2 gathers (as round 7)
        const uint32_t hx0 = cx, hx1 = cx + 1u;
        #pragma unroll
        for (int q = 0; q < 4; ++q) {
            const uint32_t idx_a = (hx0 ^ hyz[q]) & (TABLE_SIZE - 1u);
            const uint32_t idx_b = (hx1 ^ hyz[q]) & (TABLE_SIZE - 1u);
            cva[q] = *(const float2*)(tab + 2u * idx_a);
            cvb[q] = *(const float2*)(tab + 2u * idx_b);
        }
    }

    // consume in reference corner order c = 0..7 (pair q: corner 2q then 2q+1)
    float f0 = 0.0f, f1 = 0.0f;
    #pragma unroll
    for (int q = 0; q < 4; ++q) {
        const float yf = (q & 1) ? wy : wy0;
        const float zf = (q & 2) ? wz : wz0;
        const float wgt_a = (wx0 * yf) * zf;   // same assoc as rounds 1-7
        const float wgt_b = (wx  * yf) * zf;
        f0 = fmaf(wgt_a, cva[q].x, f0);
        f1 = fmaf(wgt_a, cva[q].y, f1);
        f0 = fmaf(wgt_b, cvb[q].x, f0);
        f1 = fmaf(wgt_b, cvb[q].y, f1);
    }

    a_ws[(size_t)(2 * l + 0) * n + p] = f0;
    a_ws[(size_t)(2 * l + 1) * n + p] = f1;
}

// ============================ Kernel B: MLP ============================
// Unchanged from round 7 (clean attribution of the encode experiment).
__global__ __launch_bounds__(256, 3)
void mlp_kernel(const float* __restrict__ a_ws,   // [32, N]
                const float* __restrict__ W1,     // [32,64]
                const float* __restrict__ b1,     // [64]
                const float* __restrict__ W2,     // [64,64]
                const float* __restrict__ b2,     // [64]
                const float* __restrict__ W3,     // [64,1]
                const float* __restrict__ b3,     // [1]
                float* __restrict__ out,          // [N]
                int n)
{
    const int i  = blockIdx.x * blockDim.x + threadIdx.x;
    const int ip = (i < n) ? i : (n - 1);

    float a[32];
    #pragma unroll
    for (int k = 0; k < 32; ++k)
        a[k] = a_ws[(size_t)k * n + ip];

    const v2f zero = {0.0f, 0.0f};

    v2f H1[32];
    #pragma unroll
    for (int j2 = 0; j2 < 32; ++j2) {
        const float2 b = *(const float2*)&b1[2 * j2];
        H1[j2] = (v2f){b.x, b.y};
    }
    #pragma unroll
    for (int k = 0; k < 32; ++k) {
        const float ak = a[k];
        const v2f vA = {ak, ak};
        #pragma unroll
        for (int j4 = 0; j4 < 16; ++j4) {
            const float4 w = *(const float4*)&W1[k * 64 + j4 * 4];
            H1[j4 * 2 + 0] = __builtin_elementwise_fma(vA, (v2f){w.x, w.y}, H1[j4 * 2 + 0]);
            H1[j4 * 2 + 1] = __builtin_elementwise_fma(vA, (v2f){w.z, w.w}, H1[j4 * 2 + 1]);
        }
    }
    #pragma unroll
    for (int j2 = 0; j2 < 32; ++j2)
        H1[j2] = __builtin_elementwise_max(H1[j2], zero);

    v2f acc = zero;
    #pragma unroll
    for (int half = 0; half < 2; ++half) {
        v2f H2[16];
        #pragma unroll
        for (int j2 = 0; j2 < 16; ++j2) {
            const float2 b = *(const float2*)&b2[half * 32 + 2 * j2];
            H2[j2] = (v2f){b.x, b.y};
        }
        #pragma unroll
        for (int k2 = 0; k2 < 32; ++k2) {
            const v2f hp = H1[k2];
            #pragma unroll
            for (int kk = 0; kk < 2; ++kk) {
                const float hk = kk ? hp.y : hp.x;
                const v2f vH = {hk, hk};
                const int k = 2 * k2 + kk;
                #pragma unroll
                for (int j4 = 0; j4 < 8; ++j4) {
                    const float4 w = *(const float4*)&W2[k * 64 + half * 32 + j4 * 4];
                    H2[j4 * 2 + 0] = __builtin_elementwise_fma(vH, (v2f){w.x, w.y}, H2[j4 * 2 + 0]);
                    H2[j4 * 2 + 1] = __builtin_elementwise_fma(vH, (v2f){w.z, w.w}, H2[j4 * 2 + 1]);
                }
            }
        }
        #pragma unroll
        for (int j2 = 0; j2 < 16; ++j2) {
            const float2 w3 = *(const float2*)&W3[half * 32 + 2 * j2];
            acc = __builtin_elementwise_fma(__builtin_elementwise_max(H2[j2], zero),
                                            (v2f){w3.x, w3.y}, acc);
        }
    }

    out[ip] = acc.x + acc.y + b3[0];
}

// ==================== Fallback: round-4 fused kernel ====================
__global__ __launch_bounds__(256, 4)
void hashgrid_mlp_fused(const float* __restrict__ x,
                        const float* __restrict__ tables,
                        const float* __restrict__ resolutions,
                        const float* __restrict__ W1,
                        const float* __restrict__ b1,
                        const float* __restrict__ W2,
                        const float* __restrict__ b2,
                        const float* __restrict__ W3,
                        const float* __restrict__ b3,
                        float* __restrict__ out,
                        int n)
{
    const int i  = blockIdx.x * blockDim.x + threadIdx.x;
    const int ip = (i < n) ? i : (n - 1);

    const float x0 = x[3 * ip + 0] * 0.5f + 0.5f;
    const float x1 = x[3 * ip + 1] * 0.5f + 0.5f;
    const float x2 = x[3 * ip + 2] * 0.5f + 0.5f;

    float h1[64];
    #pragma unroll
    for (int j = 0; j < 64; ++j) h1[j] = b1[j];

    #pragma unroll
    for (int l = 0; l < N_LEVELS; ++l) {
        const float res = resolutions[l];
        const float px = x0 * res, py = x1 * res, pz = x2 * res;
        const float fx = floorf(px), fy = floorf(py), fz = floorf(pz);
        const float wx = px - fx, wy = py - fy, wz = pz - fz;
        const uint32_t cx = (uint32_t)fx;
        const uint32_t cy = (uint32_t)fy;
        const uint32_t cz = (uint32_t)fz;
        const uint32_t hx0 = cx,           hx1 = cx + 1u;
        const uint32_t hy0 = cy * PRIME_Y, hy1 = hy0 + PRIME_Y;
        const uint32_t hz0 = cz * PRIME_Z, hz1 = hz0 + PRIME_Z;
        const float wx0 = 1.0f - wx, wy0 = 1.0f - wy, wz0 = 1.0f - wz;
        const float* __restrict__ tab = tables + (size_t)l * (size_t)TABLE_SIZE * 2u;

        float f0 = 0.0f, f1 = 0.0f;
        #pragma unroll
        for (int c = 0; c < 8; ++c) {
            const uint32_t h = ((c & 1) ? hx1 : hx0) ^
                               ((c & 2) ? hy1 : hy0) ^
                               ((c & 4) ? hz1 : hz0);
            const uint32_t idx = h & (TABLE_SIZE - 1u);
            const float2 fv = *(const float2*)(tab + 2u * idx);
            const float wgt = ((c & 1) ? wx : wx0) *
                              ((c & 2) ? wy : wy0) *
                              ((c & 4) ? wz : wz0);
            f0 = fmaf(wgt, fv.x, f0);
            f1 = fmaf(wgt, fv.y, f1);
        }
        const float* __restrict__ w1a = W1 + (2 * l + 0) * 64;
        const float* __restrict__ w1b = W1 + (2 * l + 1) * 64;
        #pragma unroll
        for (int j = 0; j < 64; ++j)
            h1[j] = fmaf(f1, w1b[j], fmaf(f0, w1a[j], h1[j]));
    }

    #pragma unroll
    for (int j = 0; j < 64; ++j) h1[j] = fmaxf(h1[j], 0.0f);

    float accum = b3[0];
    #pragma unroll
    for (int half = 0; half < 2; ++half) {
        float h2[32];
        #pragma unroll
        for (int j = 0; j < 32; ++j) h2[j] = b2[half * 32 + j];
        #pragma unroll
        for (int k = 0; k < 64; ++k) {
            const float hk = h1[k];
            const float* __restrict__ w2row = W2 + k * 64 + half * 32;
            #pragma unroll
            for (int j = 0; j < 32; ++j)
                h2[j] = fmaf(hk, w2row[j], h2[j]);
        }
        #pragma unroll
        for (int j = 0; j < 32; ++j)
            accum = fmaf(fmaxf(h2[j], 0.0f), W3[half * 32 + j], accum);
    }
    out[ip] = accum;
}

extern "C" void kernel_launch(void* const* d_in, const int* in_sizes, int n_in,
                              void* d_out, int out_size, void* d_ws, size_t ws_size,
                              hipStream_t stream) {
    const float* x           = (const float*)d_in[0];
    const float* tables      = (const float*)d_in[1];
    const float* resolutions = (const float*)d_in[2];
    const float* W1          = (const float*)d_in[3];
    const float* b1          = (const float*)d_in[4];
    const float* W2          = (const float*)d_in[5];
    const float* b2          = (const float*)d_in[6];
    const float* W3          = (const float*)d_in[7];
    const float* b3          = (const float*)d_in[8];
    float* out               = (float*)d_out;

    const int n = out_size;  // 2,000,000
    const int block = 256;
    const size_t ws_needed = (size_t)n * 32u * sizeof(float);

    if (ws_size >= ws_needed) {
        float* a_ws = (float*)d_ws;
        const int grid_x = (n + block - 1) / block;
        dim3 grid_enc(grid_x, N_LEVELS);   // y = level, slow-varying
        encode_kernel<<<grid_enc, block, 0, stream>>>(x, tables, resolutions, a_ws, n);
        mlp_kernel<<<grid_x, block, 0, stream>>>(a_ws, W1, b1, W2, b2, W3, b3, out, n);
    } else {
        const int grid = (n + block - 1) / block;
        hashgrid_mlp_fused<<<grid, block, 0, stream>>>(
            x, tables, resolutions, W1, b1, W2, b2, W3, b3, out, n);
    }
}

// Round 9
// 778.827 us; speedup vs baseline: 2.6568x; 1.2860x over previous
//
#include <hip/hip_runtime.h>
#include <hip/hip_bf16.h>
#include <stdint.h>

#define N_LEVELS   16
#define LOG2_T     19
#define TABLE_SIZE (1u << LOG2_T)
#define PRIME_Y    2654435761u
#define PRIME_Z    805459861u

typedef float v2f __attribute__((ext_vector_type(2)));
typedef float v4f __attribute__((ext_vector_type(4)));
typedef _Float16 v8h __attribute__((ext_vector_type(8)));

// ============================ Kernel A: encode ============================
// Round-8 version (x-corner pair merging, level-major). At the L2
// request-rate floor: 6 requests/pt/level avg -> 623 us. Unchanged.
__global__ __launch_bounds__(256, 8)
void encode_kernel(const float* __restrict__ x,           // [N,3]
                   const float* __restrict__ tables,      // [16, T, 2]
                   const float* __restrict__ resolutions, // [16]
                   float* __restrict__ a_ws,              // [32, N]
                   int n)
{
    const int l = blockIdx.y;
    int p = blockIdx.x * blockDim.x + threadIdx.x;
    if (p >= n) p = n - 1;

    const float x0 = x[3 * p + 0] * 0.5f + 0.5f;
    const float x1 = x[3 * p + 1] * 0.5f + 0.5f;
    const float x2 = x[3 * p + 2] * 0.5f + 0.5f;

    const float res = resolutions[l];
    const float px = x0 * res, py = x1 * res, pz = x2 * res;
    const float fx = floorf(px), fy = floorf(py), fz = floorf(pz);
    const float wx = px - fx, wy = py - fy, wz = pz - fz;
    const uint32_t cx = (uint32_t)fx;
    const uint32_t cy = (uint32_t)fy;
    const uint32_t cz = (uint32_t)fz;

    const uint32_t hy0 = cy * PRIME_Y, hy1 = hy0 + PRIME_Y;
    const uint32_t hz0 = cz * PRIME_Z, hz1 = hz0 + PRIME_Z;

    const float wx0 = 1.0f - wx, wy0 = 1.0f - wy, wz0 = 1.0f - wz;

    const float* __restrict__ tab = tables + (size_t)l * (size_t)TABLE_SIZE * 2u;

    const uint32_t hyz[4] = { hy0 ^ hz0, hy1 ^ hz0, hy0 ^ hz1, hy1 ^ hz1 };

    float2 cva[4], cvb[4];

    if ((cx & 1u) == 0u) {
        #pragma unroll
        for (int q = 0; q < 4; ++q) {
            const uint32_t idx_a = (cx ^ hyz[q]) & (TABLE_SIZE - 1u);
            const uint32_t base  = idx_a & ~1u;
            const float4 f4 = *(const float4*)(tab + 2u * base);
            const bool hi = (idx_a & 1u) != 0u;
            cva[q] = hi ? make_float2(f4.z, f4.w) : make_float2(f4.x, f4.y);
            cvb[q] = hi ? make_float2(f4.x, f4.y) : make_float2(f4.z, f4.w);
        }
    } else {
        const uint32_t hx0 = cx, hx1 = cx + 1u;
        #pragma unroll
        for (int q = 0; q < 4; ++q) {
            const uint32_t idx_a = (hx0 ^ hyz[q]) & (TABLE_SIZE - 1u);
            const uint32_t idx_b = (hx1 ^ hyz[q]) & (TABLE_SIZE - 1u);
            cva[q] = *(const float2*)(tab + 2u * idx_a);
            cvb[q] = *(const float2*)(tab + 2u * idx_b);
        }
    }

    float f0 = 0.0f, f1 = 0.0f;
    #pragma unroll
    for (int q = 0; q < 4; ++q) {
        const float yf = (q & 1) ? wy : wy0;
        const float zf = (q & 2) ? wz : wz0;
        const float wgt_a = (wx0 * yf) * zf;
        const float wgt_b = (wx  * yf) * zf;
        f0 = fmaf(wgt_a, cva[q].x, f0);
        f1 = fmaf(wgt_a, cva[q].y, f1);
        f0 = fmaf(wgt_b, cvb[q].x, f0);
        f1 = fmaf(wgt_b, cvb[q].y, f1);
    }

    a_ws[(size_t)(2 * l + 0) * n + p] = f0;
    a_ws[(size_t)(2 * l + 1) * n + p] = f1;
}

// ============================ Kernel B: MFMA MLP ============================
// D[ch][pt] = W^T . act orientation, 16 points per wave-tile.
// Layouts (guide, HW-verified m89/m91/m120):
//   A-frag: A[m=lane&15][k=quad*8+j]   (weights W^T: A[ch][k] = W[k][ch])
//   B-frag: B[k=quad*8+j][n=lane&15]   (activations: reads a_ws [32,N] direct)
//   C/D   : col(=pt)=lane&15, row(=ch within tile)=quad*4+reg
// f16 with exact x256 scaling (a ~1e-4 is f16-subnormal unscaled; relu is
// positively homogeneous so scale passes through; /256 in epilogue).
// Weights+biases preloaded per wave once, amortized over ~20 tiles via
// grid-stride loop. No __syncthreads (wave-private LDS + threadfence_block).
__global__ __launch_bounds__(256, 2)
void mlp_mfma_kernel(const float* __restrict__ a_ws,   // [32, N]
                     const float* __restrict__ W1,     // [32,64]
                     const float* __restrict__ b1,     // [64]
                     const float* __restrict__ W2,     // [64,64]
                     const float* __restrict__ b2,     // [64]
                     const float* __restrict__ W3,     // [64,1]
                     const float* __restrict__ b3,     // [1]
                     float* __restrict__ out,          // [N]
                     int n)
{
    __shared__ float lds[4 * 64 * 16];   // 4 KB per wave (f32 h1 staging)

    const int lane    = threadIdx.x & 63;
    const int wave_id = threadIdx.x >> 6;
    const int m       = lane & 15;        // pt within tile / ch within A-tile
    const int q       = lane >> 4;        // quad 0..3
    float* __restrict__ myl = &lds[wave_id * 1024];

    const float b3s = b3[0];

    // ---- per-wave weight/bias preload (once; amortized over tiles) ----
    v8h a1[4];                    // W1^T A-frags, 4 ch-tiles
    #pragma unroll
    for (int t = 0; t < 4; ++t)
        #pragma unroll
        for (int j = 0; j < 8; ++j)
            a1[t][j] = (_Float16)W1[(8 * q + j) * 64 + 16 * t + m];

    v8h a2[2][4];                 // W2^T A-frags, 2 k-chunks x 4 ch-tiles
    #pragma unroll
    for (int c = 0; c < 2; ++c)
        #pragma unroll
        for (int t = 0; t < 4; ++t)
            #pragma unroll
            for (int j = 0; j < 8; ++j)
                a2[c][t][j] = (_Float16)W2[(32 * c + 8 * q + j) * 64 + 16 * t + m];

    float bias1v[16], bias2v[16], w3v[16];
    #pragma unroll
    for (int t = 0; t < 4; ++t)
        #pragma unroll
        for (int r = 0; r < 4; ++r) {
            const int ch = 16 * t + 4 * q + r;
            bias1v[4 * t + r] = 256.0f * b1[ch];
            bias2v[4 * t + r] = 256.0f * b2[ch];
            w3v[4 * t + r]    = W3[ch];
        }

    // ---- grid-stride over 16-point tiles ----
    const int nt = (n + 15) >> 4;
    const int total_waves = gridDim.x * 4;
    const int gw = blockIdx.x * 4 + wave_id;

    for (int tile = gw; tile < nt; tile += total_waves) {
        const int p0 = tile * 16;
        const int pr = (p0 + m < n) ? (p0 + m) : (n - 1);  // clamped read

        // B-frag for layer 1: k = q*8+j over all 32 feats, n = pt
        v8h bh;
        #pragma unroll
        for (int j = 0; j < 8; ++j)
            bh[j] = (_Float16)(a_ws[(size_t)(8 * q + j) * n + pr] * 256.0f);

        // ---- layer 1: 4 MFMA ----
        v4f acc1[4];
        #pragma unroll
        for (int t = 0; t < 4; ++t) {
            #pragma unroll
            for (int r = 0; r < 4; ++r) acc1[t][r] = bias1v[4 * t + r];
            acc1[t] = __builtin_amdgcn_mfma_f32_16x16x32_f16(a1[t], bh, acc1[t], 0, 0, 0);
        }

        // relu + stage h1 (f32) to wave-private LDS in [ch][pt] layout
        #pragma unroll
        for (int t = 0; t < 4; ++t)
            #pragma unroll
            for (int r = 0; r < 4; ++r) {
                const float v = fmaxf(acc1[t][r], 0.0f);
                myl[(16 * t + 4 * q + r) * 16 + m] = v;
            }
        __threadfence_block();   // order ds_write -> ds_read within wave

        // read back as B-frags for layer 2 (k-chunks of 32)
        v8h b2h[2];
        #pragma unroll
        for (int c = 0; c < 2; ++c)
            #pragma unroll
            for (int j = 0; j < 8; ++j)
                b2h[c][j] = (_Float16)myl[(32 * c + 8 * q + j) * 16 + m];

        // ---- layer 2: 8 MFMA ----
        v4f acc2[4];
        #pragma unroll
        for (int t = 0; t < 4; ++t) {
            #pragma unroll
            for (int r = 0; r < 4; ++r) acc2[t][r] = bias2v[4 * t + r];
            acc2[t] = __builtin_amdgcn_mfma_f32_16x16x32_f16(a2[0][t], b2h[0], acc2[t], 0, 0, 0);
            acc2[t] = __builtin_amdgcn_mfma_f32_16x16x32_f16(a2[1][t], b2h[1], acc2[t], 0, 0, 0);
        }

        // ---- layer 3 epilogue: relu, dot with W3, cross-quad reduce ----
        float partial = 0.0f;
        #pragma unroll
        for (int t = 0; t < 4; ++t)
            #pragma unroll
            for (int r = 0; r < 4; ++r)
                partial = fmaf(fmaxf(acc2[t][r], 0.0f), w3v[4 * t + r], partial);

        partial += __shfl_xor(partial, 16);
        partial += __shfl_xor(partial, 32);

        if (q == 0 && p0 + m < n)
            out[p0 + m] = partial * (1.0f / 256.0f) + b3s;
    }
}

// ==================== Fallback: round-4 fused kernel ====================
__global__ __launch_bounds__(256, 4)
void hashgrid_mlp_fused(const float* __restrict__ x,
                        const float* __restrict__ tables,
                        const float* __restrict__ resolutions,
                        const float* __restrict__ W1,
                        const float* __restrict__ b1,
                        const float* __restrict__ W2,
                        const float* __restrict__ b2,
                        const float* __restrict__ W3,
                        const float* __restrict__ b3,
                        float* __restrict__ out,
                        int n)
{
    const int i  = blockIdx.x * blockDim.x + threadIdx.x;
    const int ip = (i < n) ? i : (n - 1);

    const float x0 = x[3 * ip + 0] * 0.5f + 0.5f;
    const float x1 = x[3 * ip + 1] * 0.5f + 0.5f;
    const float x2 = x[3 * ip + 2] * 0.5f + 0.5f;

    float h1[64];
    #pragma unroll
    for (int j = 0; j < 64; ++j) h1[j] = b1[j];

    #pragma unroll
    for (int l = 0; l < N_LEVELS; ++l) {
        const float res = resolutions[l];
        const float px = x0 * res, py = x1 * res, pz = x2 * res;
        const float fx = floorf(px), fy = floorf(py), fz = floorf(pz);
        const float wx = px - fx, wy = py - fy, wz = pz - fz;
        const uint32_t cx = (uint32_t)fx;
        const uint32_t cy = (uint32_t)fy;
        const uint32_t cz = (uint32_t)fz;
        const uint32_t hx0 = cx,           hx1 = cx + 1u;
        const uint32_t hy0 = cy * PRIME_Y, hy1 = hy0 + PRIME_Y;
        const uint32_t hz0 = cz * PRIME_Z, hz1 = hz0 + PRIME_Z;
        const float wx0 = 1.0f - wx, wy0 = 1.0f - wy, wz0 = 1.0f - wz;
        const float* __restrict__ tab = tables + (size_t)l * (size_t)TABLE_SIZE * 2u;

        float f0 = 0.0f, f1 = 0.0f;
        #pragma unroll
        for (int c = 0; c < 8; ++c) {
            const uint32_t h = ((c & 1) ? hx1 : hx0) ^
                               ((c & 2) ? hy1 : hy0) ^
                               ((c & 4) ? hz1 : hz0);
            const uint32_t idx = h & (TABLE_SIZE - 1u);
            const float2 fv = *(const float2*)(tab + 2u * idx);
            const float wgt = ((c & 1) ? wx : wx0) *
                              ((c & 2) ? wy : wy0) *
                              ((c & 4) ? wz : wz0);
            f0 = fmaf(wgt, fv.x, f0);
            f1 = fmaf(wgt, fv.y, f1);
        }
        const float* __restrict__ w1a = W1 + (2 * l + 0) * 64;
        const float* __restrict__ w1b = W1 + (2 * l + 1) * 64;
        #pragma unroll
        for (int j = 0; j < 64; ++j)
            h1[j] = fmaf(f1, w1b[j], fmaf(f0, w1a[j], h1[j]));
    }

    #pragma unroll
    for (int j = 0; j < 64; ++j) h1[j] = fmaxf(h1[j], 0.0f);

    float accum = b3[0];
    #pragma unroll
    for (int half = 0; half < 2; ++half) {
        float h2[32];
        #pragma unroll
        for (int j = 0; j < 32; ++j) h2[j] = b2[half * 32 + j];
        #pragma unroll
        for (int k = 0; k < 64; ++k) {
            const float hk = h1[k];
            const float* __restrict__ w2row = W2 + k * 64 + half * 32;
            #pragma unroll
            for (int j = 0; j < 32; ++j)
                h2[j] = fmaf(hk, w2row[j], h2[j]);
        }
        #pragma unroll
        for (int j = 0; j < 32; ++j)
            accum = fmaf(fmaxf(h2[j], 0.0f), W3[half * 32 + j], accum);
    }
    out[ip] = accum;
}

extern "C" void kernel_launch(void* const* d_in, const int* in_sizes, int n_in,
                              void* d_out, int out_size, void* d_ws, size_t ws_size,
                              hipStream_t stream) {
    const float* x           = (const float*)d_in[0];
    const float* tables      = (const float*)d_in[1];
    const float* resolutions = (const float*)d_in[2];
    const float* W1          = (const float*)d_in[3];
    const float* b1          = (const float*)d_in[4];
    const float* W2          = (const float*)d_in[5];
    const float* b2          = (const float*)d_in[6];
    const float* W3          = (const float*)d_in[7];
    const float* b3          = (const float*)d_in[8];
    float* out               = (float*)d_out;

    const int n = out_size;  // 2,000,000
    const int block = 256;
    const size_t ws_needed = (size_t)n * 32u * sizeof(float);

    if (ws_size >= ws_needed) {
        float* a_ws = (float*)d_ws;
        const int grid_x = (n + block - 1) / block;
        dim3 grid_enc(grid_x, N_LEVELS);   // y = level, slow-varying
        encode_kernel<<<grid_enc, block, 0, stream>>>(x, tables, resolutions, a_ws, n);
        mlp_mfma_kernel<<<1536, block, 0, stream>>>(a_ws, W1, b1, W2, b2, W3, b3, out, n);
    } else {
        const int grid = (n + block - 1) / block;
        hashgrid_mlp_fused<<<grid, block, 0, stream>>>(
            x, tables, resolutions, W1, b1, W2, b2, W3, b3, out, n);
    }
}

// Round 10
// 716.877 us; speedup vs baseline: 2.8864x; 1.0864x over previous
//
#include <hip/hip_runtime.h>
#include <hip/hip_bf16.h>
#include <stdint.h>

#define N_LEVELS   16
#define LOG2_T     19
#define TABLE_SIZE (1u << LOG2_T)
#define PRIME_Y    2654435761u
#define PRIME_Z    805459861u
#define NBUCK      262144     // 64^3 Morton buckets = 1024 * 256

typedef float v4f __attribute__((ext_vector_type(4)));
typedef _Float16 v8h __attribute__((ext_vector_type(8)));

// ---------------- Morton key (bucketing only; any key is correct) ----------
__device__ __forceinline__ uint32_t part1by2(uint32_t v) {
    v &= 0x3FFu;
    v = (v | (v << 16)) & 0x030000FFu;
    v = (v | (v <<  8)) & 0x0300F00Fu;
    v = (v | (v <<  4)) & 0x030C30C3u;
    v = (v | (v <<  2)) & 0x09249249u;
    return v;
}
__device__ __forceinline__ uint32_t morton_key(float xr, float yr, float zr) {
    int vx = (int)((xr * 0.5f + 0.5f) * 64.0f);
    int vy = (int)((yr * 0.5f + 0.5f) * 64.0f);
    int vz = (int)((zr * 0.5f + 0.5f) * 64.0f);
    vx = vx < 0 ? 0 : (vx > 63 ? 63 : vx);
    vy = vy < 0 ? 0 : (vy > 63 ? 63 : vy);
    vz = vz < 0 ? 0 : (vz > 63 ? 63 : vz);
    return part1by2((uint32_t)vx) | (part1by2((uint32_t)vy) << 1)
         | (part1by2((uint32_t)vz) << 2);
}

// ---------------- sort pipeline ----------------
__global__ void hist_kernel(const float* __restrict__ x, int* __restrict__ counts, int n) {
    const int i = blockIdx.x * blockDim.x + threadIdx.x;
    if (i >= n) return;
    const uint32_t key = morton_key(x[3*i], x[3*i+1], x[3*i+2]);
    atomicAdd(&counts[key], 1);
}

__global__ void scan_block_kernel(const int* __restrict__ counts,
                                  int* __restrict__ prefix,
                                  int* __restrict__ blocksum) {
    __shared__ int s[256];
    const int t = threadIdx.x;
    const int i = blockIdx.x * 256 + t;
    const int v = counts[i];
    s[t] = v; __syncthreads();
    #pragma unroll
    for (int d = 1; d < 256; d <<= 1) {
        const int u = (t >= d) ? s[t - d] : 0;
        __syncthreads();
        s[t] += u;
        __syncthreads();
    }
    prefix[i] = s[t] - v;                 // exclusive within block
    if (t == 255) blocksum[blockIdx.x] = s[255];
}

__global__ void scan_top_kernel(const int* __restrict__ blocksum,
                                int* __restrict__ blockbase) {
    __shared__ int s[1024];
    const int t = threadIdx.x;
    const int v = blocksum[t];
    s[t] = v; __syncthreads();
    #pragma unroll
    for (int d = 1; d < 1024; d <<= 1) {
        const int u = (t >= d) ? s[t - d] : 0;
        __syncthreads();
        s[t] += u;
        __syncthreads();
    }
    blockbase[t] = s[t] - v;              // exclusive
}

__global__ void addback_kernel(const int* __restrict__ prefix,
                               const int* __restrict__ blockbase,
                               int* __restrict__ offsets) {
    const int i = blockIdx.x * 256 + threadIdx.x;
    offsets[i] = prefix[i] + blockbase[i >> 8];
}

// scatter: x_sorted in SoA [3][N] (coalesced reads in encode), pid[pos]=orig idx
__global__ void scatter_kernel(const float* __restrict__ x,
                               int* __restrict__ offsets,     // consumed
                               float* __restrict__ xs,        // [3][N]
                               int* __restrict__ pid,         // [N]
                               int n) {
    const int i = blockIdx.x * blockDim.x + threadIdx.x;
    if (i >= n) return;
    const float a = x[3*i], b = x[3*i+1], c = x[3*i+2];
    const uint32_t key = morton_key(a, b, c);
    const int pos = atomicAdd(&offsets[key], 1);
    xs[pos]       = a;
    xs[n + pos]   = b;
    xs[2*n + pos] = c;
    pid[pos]      = i;
}

// ============================ encode ============================
// Round-8 core (level-major + x-corner pair merging) over SORTED points:
// adjacent lanes are spatially adjacent -> TCP merges same-line lanes into
// one L2 request (big at coarse levels). a_ws stored f16 x256 (bit-identical
// to the mlp's previous (f16)(a*256) conversion).
__global__ __launch_bounds__(256, 8)
void encode_kernel(const float* __restrict__ xs,          // [3][N] sorted
                   const float* __restrict__ tables,      // [16, T, 2]
                   const float* __restrict__ resolutions, // [16]
                   _Float16* __restrict__ a_ws,           // [32][N] f16, x256
                   int n)
{
    const int l = blockIdx.y;
    int p = blockIdx.x * blockDim.x + threadIdx.x;
    if (p >= n) p = n - 1;

    const float x0 = xs[p]       * 0.5f + 0.5f;
    const float x1 = xs[n + p]   * 0.5f + 0.5f;
    const float x2 = xs[2*n + p] * 0.5f + 0.5f;

    const float res = resolutions[l];
    const float px = x0 * res, py = x1 * res, pz = x2 * res;
    const float fx = floorf(px), fy = floorf(py), fz = floorf(pz);
    const float wx = px - fx, wy = py - fy, wz = pz - fz;
    const uint32_t cx = (uint32_t)fx;
    const uint32_t cy = (uint32_t)fy;
    const uint32_t cz = (uint32_t)fz;

    const uint32_t hy0 = cy * PRIME_Y, hy1 = hy0 + PRIME_Y;
    const uint32_t hz0 = cz * PRIME_Z, hz1 = hz0 + PRIME_Z;

    const float wx0 = 1.0f - wx, wy0 = 1.0f - wy, wz0 = 1.0f - wz;

    const float* __restrict__ tab = tables + (size_t)l * (size_t)TABLE_SIZE * 2u;

    const uint32_t hyz[4] = { hy0 ^ hz0, hy1 ^ hz0, hy0 ^ hz1, hy1 ^ hz1 };

    float2 cva[4], cvb[4];

    if ((cx & 1u) == 0u) {
        #pragma unroll
        for (int q = 0; q < 4; ++q) {
            const uint32_t idx_a = (cx ^ hyz[q]) & (TABLE_SIZE - 1u);
            const uint32_t base  = idx_a & ~1u;
            const float4 f4 = *(const float4*)(tab + 2u * base);
            const bool hi = (idx_a & 1u) != 0u;
            cva[q] = hi ? make_float2(f4.z, f4.w) : make_float2(f4.x, f4.y);
            cvb[q] = hi ? make_float2(f4.x, f4.y) : make_float2(f4.z, f4.w);
        }
    } else {
        const uint32_t hx0 = cx, hx1 = cx + 1u;
        #pragma unroll
        for (int q = 0; q < 4; ++q) {
            const uint32_t idx_a = (hx0 ^ hyz[q]) & (TABLE_SIZE - 1u);
            const uint32_t idx_b = (hx1 ^ hyz[q]) & (TABLE_SIZE - 1u);
            cva[q] = *(const float2*)(tab + 2u * idx_a);
            cvb[q] = *(const float2*)(tab + 2u * idx_b);
        }
    }

    float f0 = 0.0f, f1 = 0.0f;
    #pragma unroll
    for (int q = 0; q < 4; ++q) {
        const float yf = (q & 1) ? wy : wy0;
        const float zf = (q & 2) ? wz : wz0;
        const float wgt_a = (wx0 * yf) * zf;
        const float wgt_b = (wx  * yf) * zf;
        f0 = fmaf(wgt_a, cva[q].x, f0);
        f1 = fmaf(wgt_a, cva[q].y, f1);
        f0 = fmaf(wgt_b, cvb[q].x, f0);
        f1 = fmaf(wgt_b, cvb[q].y, f1);
    }

    a_ws[(size_t)(2 * l + 0) * n + p] = (_Float16)(f0 * 256.0f);
    a_ws[(size_t)(2 * l + 1) * n + p] = (_Float16)(f1 * 256.0f);
}

// ============================ MFMA MLP ============================
// Round-9 structure + f16 a_ws direct into B-frags (no cvt/scale) +
// software-pipelined tile loop + scatter-out via pid.
__global__ __launch_bounds__(256, 2)
void mlp_mfma_kernel(const _Float16* __restrict__ a_ws,  // [32][N] f16 x256
                     const int* __restrict__ pid,        // [N] sorted->orig
                     const float* __restrict__ W1,
                     const float* __restrict__ b1,
                     const float* __restrict__ W2,
                     const float* __restrict__ b2,
                     const float* __restrict__ W3,
                     const float* __restrict__ b3,
                     float* __restrict__ out,
                     int n)
{
    __shared__ float lds[4 * 64 * 16];

    const int lane    = threadIdx.x & 63;
    const int wave_id = threadIdx.x >> 6;
    const int m       = lane & 15;
    const int q       = lane >> 4;
    float* __restrict__ myl = &lds[wave_id * 1024];

    const float b3s = b3[0];

    v8h a1[4];
    #pragma unroll
    for (int t = 0; t < 4; ++t)
        #pragma unroll
        for (int j = 0; j < 8; ++j)
            a1[t][j] = (_Float16)W1[(8 * q + j) * 64 + 16 * t + m];

    v8h a2[2][4];
    #pragma unroll
    for (int c = 0; c < 2; ++c)
        #pragma unroll
        for (int t = 0; t < 4; ++t)
            #pragma unroll
            for (int j = 0; j < 8; ++j)
                a2[c][t][j] = (_Float16)W2[(32 * c + 8 * q + j) * 64 + 16 * t + m];

    float bias1v[16], bias2v[16], w3v[16];
    #pragma unroll
    for (int t = 0; t < 4; ++t)
        #pragma unroll
        for (int r = 0; r < 4; ++r) {
            const int ch = 16 * t + 4 * q + r;
            bias1v[4 * t + r] = 256.0f * b1[ch];
            bias2v[4 * t + r] = 256.0f * b2[ch];
            w3v[4 * t + r]    = W3[ch];
        }

    const int nt = (n + 15) >> 4;
    const int stride = gridDim.x * 4;
    const int gw = blockIdx.x * 4 + wave_id;
    if (gw >= nt) return;

    v8h bh;
    {
        const int p0 = gw * 16;
        const int pr = (p0 + m < n) ? (p0 + m) : (n - 1);
        #pragma unroll
        for (int j = 0; j < 8; ++j)
            bh[j] = a_ws[(size_t)(8 * q + j) * n + pr];
    }

    for (int tile = gw; tile < nt; tile += stride) {
        const int p0 = tile * 16;

        v8h bhn = bh;
        const int nx = tile + stride;
        if (nx < nt) {
            const int p0n = nx * 16;
            const int prn = (p0n + m < n) ? (p0n + m) : (n - 1);
            #pragma unroll
            for (int j = 0; j < 8; ++j)
                bhn[j] = a_ws[(size_t)(8 * q + j) * n + prn];
        }
        const int po = (p0 + m < n) ? pid[p0 + m] : 0;

        v4f acc1[4];
        #pragma unroll
        for (int t = 0; t < 4; ++t) {
            #pragma unroll
            for (int r = 0; r < 4; ++r) acc1[t][r] = bias1v[4 * t + r];
            acc1[t] = __builtin_amdgcn_mfma_f32_16x16x32_f16(a1[t], bh, acc1[t], 0, 0, 0);
        }

        #pragma unroll
        for (int t = 0; t < 4; ++t)
            #pragma unroll
            for (int r = 0; r < 4; ++r)
                myl[(16 * t + 4 * q + r) * 16 + m] = fmaxf(acc1[t][r], 0.0f);
        __threadfence_block();

        v8h b2h[2];
        #pragma unroll
        for (int c = 0; c < 2; ++c)
            #pragma unroll
            for (int j = 0; j < 8; ++j)
                b2h[c][j] = (_Float16)myl[(32 * c + 8 * q + j) * 16 + m];

        v4f acc2[4];
        #pragma unroll
        for (int t = 0; t < 4; ++t) {
            #pragma unroll
            for (int r = 0; r < 4; ++r) acc2[t][r] = bias2v[4 * t + r];
            acc2[t] = __builtin_amdgcn_mfma_f32_16x16x32_f16(a2[0][t], b2h[0], acc2[t], 0, 0, 0);
            acc2[t] = __builtin_amdgcn_mfma_f32_16x16x32_f16(a2[1][t], b2h[1], acc2[t], 0, 0, 0);
        }

        float partial = 0.0f;
        #pragma unroll
        for (int t = 0; t < 4; ++t)
            #pragma unroll
            for (int r = 0; r < 4; ++r)
                partial = fmaf(fmaxf(acc2[t][r], 0.0f), w3v[4 * t + r], partial);

        partial += __shfl_xor(partial, 16);
        partial += __shfl_xor(partial, 32);

        if (q == 0 && p0 + m < n)
            out[po] = partial * (1.0f / 256.0f) + b3s;

        bh = bhn;
    }
}

// ==================== Fallback: round-4 fused kernel ====================
__global__ __launch_bounds__(256, 4)
void hashgrid_mlp_fused(const float* __restrict__ x,
                        const float* __restrict__ tables,
                        const float* __restrict__ resolutions,
                        const float* __restrict__ W1,
                        const float* __restrict__ b1,
                        const float* __restrict__ W2,
                        const float* __restrict__ b2,
                        const float* __restrict__ W3,
                        const float* __restrict__ b3,
                        float* __restrict__ out,
                        int n)
{
    const int i  = blockIdx.x * blockDim.x + threadIdx.x;
    const int ip = (i < n) ? i : (n - 1);

    const float x0 = x[3 * ip + 0] * 0.5f + 0.5f;
    const float x1 = x[3 * ip + 1] * 0.5f + 0.5f;
    const float x2 = x[3 * ip + 2] * 0.5f + 0.5f;

    float h1[64];
    #pragma unroll
    for (int j = 0; j < 64; ++j) h1[j] = b1[j];

    #pragma unroll
    for (int l = 0; l < N_LEVELS; ++l) {
        const float res = resolutions[l];
        const float px = x0 * res, py = x1 * res, pz = x2 * res;
        const float fx = floorf(px), fy = floorf(py), fz = floorf(pz);
        const float wx = px - fx, wy = py - fy, wz = pz - fz;
        const uint32_t cx = (uint32_t)fx;
        const uint32_t cy = (uint32_t)fy;
        const uint32_t cz = (uint32_t)fz;
        const uint32_t hx0 = cx,           hx1 = cx + 1u;
        const uint32_t hy0 = cy * PRIME_Y, hy1 = hy0 + PRIME_Y;
        const uint32_t hz0 = cz * PRIME_Z, hz1 = hz0 + PRIME_Z;
        const float wx0 = 1.0f - wx, wy0 = 1.0f - wy, wz0 = 1.0f - wz;
        const float* __restrict__ tab = tables + (size_t)l * (size_t)TABLE_SIZE * 2u;

        float f0 = 0.0f, f1 = 0.0f;
        #pragma unroll
        for (int c = 0; c < 8; ++c) {
            const uint32_t h = ((c & 1) ? hx1 : hx0) ^
                               ((c & 2) ? hy1 : hy0) ^
                               ((c & 4) ? hz1 : hz0);
            const uint32_t idx = h & (TABLE_SIZE - 1u);
            const float2 fv = *(const float2*)(tab + 2u * idx);
            const float wgt = ((c & 1) ? wx : wx0) *
                              ((c & 2) ? wy : wy0) *
                              ((c & 4) ? wz : wz0);
            f0 = fmaf(wgt, fv.x, f0);
            f1 = fmaf(wgt, fv.y, f1);
        }
        const float* __restrict__ w1a = W1 + (2 * l + 0) * 64;
        const float* __restrict__ w1b = W1 + (2 * l + 1) * 64;
        #pragma unroll
        for (int j = 0; j < 64; ++j)
            h1[j] = fmaf(f1, w1b[j], fmaf(f0, w1a[j], h1[j]));
    }

    #pragma unroll
    for (int j = 0; j < 64; ++j) h1[j] = fmaxf(h1[j], 0.0f);

    float accum = b3[0];
    #pragma unroll
    for (int half = 0; half < 2; ++half) {
        float h2[32];
        #pragma unroll
        for (int j = 0; j < 32; ++j) h2[j] = b2[half * 32 + j];
        #pragma unroll
        for (int k = 0; k < 64; ++k) {
            const float hk = h1[k];
            const float* __restrict__ w2row = W2 + k * 64 + half * 32;
            #pragma unroll
            for (int j = 0; j < 32; ++j)
                h2[j] = fmaf(hk, w2row[j], h2[j]);
        }
        #pragma unroll
        for (int j = 0; j < 32; ++j)
            accum = fmaf(fmaxf(h2[j], 0.0f), W3[half * 32 + j], accum);
    }
    out[ip] = accum;
}

extern "C" void kernel_launch(void* const* d_in, const int* in_sizes, int n_in,
                              void* d_out, int out_size, void* d_ws, size_t ws_size,
                              hipStream_t stream) {
    const float* x           = (const float*)d_in[0];
    const float* tables      = (const float*)d_in[1];
    const float* resolutions = (const float*)d_in[2];
    const float* W1          = (const float*)d_in[3];
    const float* b1          = (const float*)d_in[4];
    const float* W2          = (const float*)d_in[5];
    const float* b2          = (const float*)d_in[6];
    const float* W3          = (const float*)d_in[7];
    const float* b3          = (const float*)d_in[8];
    float* out               = (float*)d_out;

    const int n = out_size;  // 2,000,000
    const int block = 256;
    const int grid_pts = (n + block - 1) / block;

    // ---- workspace layout (256B-aligned slabs) ----
    size_t off = 0;
    #define CARVE(bytes) (off = (off + 255) & ~(size_t)255, off += (bytes), off - (bytes))
    const size_t aws_off   = CARVE((size_t)32 * n * sizeof(_Float16)); // 128 MB
    const size_t xs_off    = CARVE((size_t)3 * n * sizeof(float));     //  24 MB
    const size_t pid_off   = CARVE((size_t)n * sizeof(int));           //   8 MB
    const size_t cnt_off   = CARVE((size_t)NBUCK * sizeof(int));
    const size_t pref_off  = CARVE((size_t)NBUCK * sizeof(int));
    const size_t offs_off  = CARVE((size_t)NBUCK * sizeof(int));
    const size_t bsum_off  = CARVE(1024 * sizeof(int));
    const size_t bbase_off = CARVE(1024 * sizeof(int));
    const size_t total_ws  = off;
    #undef CARVE

    if (ws_size >= total_ws) {
        char* ws = (char*)d_ws;
        _Float16* a_ws  = (_Float16*)(ws + aws_off);
        float*    xs    = (float*)(ws + xs_off);
        int*      pid   = (int*)(ws + pid_off);
        int*      cnts  = (int*)(ws + cnt_off);
        int*      pref  = (int*)(ws + pref_off);
        int*      offs  = (int*)(ws + offs_off);
        int*      bsum  = (int*)(ws + bsum_off);
        int*      bbase = (int*)(ws + bbase_off);

        hipMemsetAsync(cnts, 0, (size_t)NBUCK * sizeof(int), stream);
        hist_kernel<<<grid_pts, block, 0, stream>>>(x, cnts, n);
        scan_block_kernel<<<NBUCK / 256, 256, 0, stream>>>(cnts, pref, bsum);
        scan_top_kernel<<<1, 1024, 0, stream>>>(bsum, bbase);
        addback_kernel<<<NBUCK / 256, 256, 0, stream>>>(pref, bbase, offs);
        scatter_kernel<<<grid_pts, block, 0, stream>>>(x, offs, xs, pid, n);

        dim3 grid_enc(grid_pts, N_LEVELS);   // y = level, slow-varying
        encode_kernel<<<grid_enc, block, 0, stream>>>(xs, tables, resolutions, a_ws, n);
        mlp_mfma_kernel<<<512, block, 0, stream>>>(a_ws, pid, W1, b1, W2, b2, W3, b3, out, n);
    } else {
        hashgrid_mlp_fused<<<grid_pts, block, 0, stream>>>(
            x, tables, resolutions, W1, b1, W2, b2, W3, b3, out, n);
    }
}

// Round 11
// 670.764 us; speedup vs baseline: 3.0848x; 1.0687x over previous
//
#include <hip/hip_runtime.h>
#include <hip/hip_bf16.h>
#include <stdint.h>

#define N_LEVELS   16
#define LOG2_T     19
#define TABLE_SIZE (1u << LOG2_T)
#define PRIME_Y    2654435761u
#define PRIME_Z    805459861u

#define NB        32768     // 32^3 buckets
#define SORT_B    256       // sort blocks (each owns a contiguous point chunk)

typedef float v4f __attribute__((ext_vector_type(4)));
typedef _Float16 v8h __attribute__((ext_vector_type(8)));

// ---------------- Morton key, 3x5 bits (bucketing only) ----------------
__device__ __forceinline__ uint32_t part1by2(uint32_t v) {
    v &= 0x3FFu;
    v = (v | (v << 16)) & 0x030000FFu;
    v = (v | (v <<  8)) & 0x0300F00Fu;
    v = (v | (v <<  4)) & 0x030C30C3u;
    v = (v | (v <<  2)) & 0x09249249u;
    return v;
}
__device__ __forceinline__ uint32_t morton_key(float xr, float yr, float zr) {
    int vx = (int)((xr * 0.5f + 0.5f) * 32.0f);
    int vy = (int)((yr * 0.5f + 0.5f) * 32.0f);
    int vz = (int)((zr * 0.5f + 0.5f) * 32.0f);
    vx = vx < 0 ? 0 : (vx > 31 ? 31 : vx);
    vy = vy < 0 ? 0 : (vy > 31 ? 31 : vy);
    vz = vz < 0 ? 0 : (vz > 31 ? 31 : vz);
    return part1by2((uint32_t)vx) | (part1by2((uint32_t)vy) << 1)
         | (part1by2((uint32_t)vz) << 2);   // 15-bit key
}

// ============== sort, NO device atomics (LDS-histogram counting sort) =====
// hist: per-block LDS histogram (2x16-bit packed, 64 KB), flushed to
// g_hist[b][key] with plain coalesced stores.
__global__ __launch_bounds__(256)
void hist_kernel(const float* __restrict__ x, uint32_t* __restrict__ g_hist,
                 int n, int chunk)
{
    __shared__ uint32_t pack[NB / 2];
    const int b = blockIdx.x, t = threadIdx.x;
    for (int w = t; w < NB / 2; w += 256) pack[w] = 0;
    __syncthreads();
    const int beg = b * chunk;
    const int end = (beg + chunk < n) ? (beg + chunk) : n;
    for (int i = beg + t; i < end; i += 256) {
        const uint32_t key = morton_key(x[3*i], x[3*i+1], x[3*i+2]);
        atomicAdd(&pack[key >> 1], 1u << ((key & 1u) << 4));
    }
    __syncthreads();
    uint32_t* __restrict__ dst = g_hist + (size_t)b * NB;
    for (int w = t; w < NB / 2; w += 256) {
        const uint32_t p = pack[w];
        dst[2*w]     = p & 0xFFFFu;
        dst[2*w + 1] = p >> 16;
    }
}

// column scan: part[b][key] = sum_{b'<b} hist[b'][key]; totals[key] = full sum
__global__ __launch_bounds__(256)
void scan_cols_kernel(const uint32_t* __restrict__ g_hist,
                      uint32_t* __restrict__ g_part,
                      uint32_t* __restrict__ totals)
{
    const int key = blockIdx.x * 256 + threadIdx.x;   // 0..NB-1
    uint32_t run = 0;
    #pragma unroll 8
    for (int b = 0; b < SORT_B; ++b) {
        const size_t idx = (size_t)b * NB + key;
        const uint32_t v = g_hist[idx];
        g_part[idx] = run;
        run += v;
    }
    totals[key] = run;
}

__global__ void scan_block_kernel(const uint32_t* __restrict__ counts,
                                  uint32_t* __restrict__ prefix,
                                  uint32_t* __restrict__ blocksum) {
    __shared__ uint32_t s[256];
    const int t = threadIdx.x;
    const int i = blockIdx.x * 256 + t;
    const uint32_t v = counts[i];
    s[t] = v; __syncthreads();
    #pragma unroll
    for (int d = 1; d < 256; d <<= 1) {
        const uint32_t u = (t >= d) ? s[t - d] : 0;
        __syncthreads();
        s[t] += u;
        __syncthreads();
    }
    prefix[i] = s[t] - v;
    if (t == 255) blocksum[blockIdx.x] = s[255];
}

__global__ void scan_top_kernel(const uint32_t* __restrict__ blocksum,
                                uint32_t* __restrict__ blockbase, int nb) {
    __shared__ uint32_t s[1024];
    const int t = threadIdx.x;
    const uint32_t v = (t < nb) ? blocksum[t] : 0;
    s[t] = v; __syncthreads();
    #pragma unroll
    for (int d = 1; d < 1024; d <<= 1) {
        const uint32_t u = (t >= d) ? s[t - d] : 0;
        __syncthreads();
        s[t] += u;
        __syncthreads();
    }
    if (t < nb) blockbase[t] = s[t] - v;
}

__global__ void addback_kernel(const uint32_t* __restrict__ prefix,
                               const uint32_t* __restrict__ blockbase,
                               uint32_t* __restrict__ base) {
    const int i = blockIdx.x * 256 + threadIdx.x;
    base[i] = prefix[i] + blockbase[i >> 8];
}

// scatter: rank from LDS counters (same packed scheme), pos = base+part+rank.
// Writes xs (SoA) + rank_inv (coalesced by original index).
__global__ __launch_bounds__(256)
void scatter_kernel(const float* __restrict__ x,
                    const uint32_t* __restrict__ base,
                    const uint32_t* __restrict__ g_part,
                    float* __restrict__ xs,        // [3][N]
                    int* __restrict__ rank_inv,    // [N] orig -> sorted pos
                    int n, int chunk)
{
    __shared__ uint32_t pack[NB / 2];
    const int b = blockIdx.x, t = threadIdx.x;
    for (int w = t; w < NB / 2; w += 256) pack[w] = 0;
    __syncthreads();
    const uint32_t* __restrict__ part = g_part + (size_t)b * NB;
    const int beg = b * chunk;
    const int end = (beg + chunk < n) ? (beg + chunk) : n;
    for (int i = beg + t; i < end; i += 256) {
        const float a = x[3*i], c = x[3*i+1], d = x[3*i+2];
        const uint32_t key = morton_key(a, c, d);
        const uint32_t sh = (key & 1u) << 4;
        uint32_t r = atomicAdd(&pack[key >> 1], 1u << sh);
        r = (r >> sh) & 0xFFFFu;
        const uint32_t pos = base[key] + part[key] + r;
        xs[pos]         = a;
        xs[n + pos]     = c;
        xs[2*n + pos]   = d;
        rank_inv[i]     = (int)pos;
    }
}

// ============================ encode ============================
// Round-10 core (level-major + x-corner pair merging), sorted input,
// f16 x256 a_ws output. Unchanged.
__global__ __launch_bounds__(256, 8)
void encode_kernel(const float* __restrict__ xs,          // [3][N] sorted
                   const float* __restrict__ tables,      // [16, T, 2]
                   const float* __restrict__ resolutions, // [16]
                   _Float16* __restrict__ a_ws,           // [32][N] f16, x256
                   int n)
{
    const int l = blockIdx.y;
    int p = blockIdx.x * blockDim.x + threadIdx.x;
    if (p >= n) p = n - 1;

    const float x0 = xs[p]       * 0.5f + 0.5f;
    const float x1 = xs[n + p]   * 0.5f + 0.5f;
    const float x2 = xs[2*n + p] * 0.5f + 0.5f;

    const float res = resolutions[l];
    const float px = x0 * res, py = x1 * res, pz = x2 * res;
    const float fx = floorf(px), fy = floorf(py), fz = floorf(pz);
    const float wx = px - fx, wy = py - fy, wz = pz - fz;
    const uint32_t cx = (uint32_t)fx;
    const uint32_t cy = (uint32_t)fy;
    const uint32_t cz = (uint32_t)fz;

    const uint32_t hy0 = cy * PRIME_Y, hy1 = hy0 + PRIME_Y;
    const uint32_t hz0 = cz * PRIME_Z, hz1 = hz0 + PRIME_Z;

    const float wx0 = 1.0f - wx, wy0 = 1.0f - wy, wz0 = 1.0f - wz;

    const float* __restrict__ tab = tables + (size_t)l * (size_t)TABLE_SIZE * 2u;

    const uint32_t hyz[4] = { hy0 ^ hz0, hy1 ^ hz0, hy0 ^ hz1, hy1 ^ hz1 };

    float2 cva[4], cvb[4];

    if ((cx & 1u) == 0u) {
        #pragma unroll
        for (int q = 0; q < 4; ++q) {
            const uint32_t idx_a = (cx ^ hyz[q]) & (TABLE_SIZE - 1u);
            const uint32_t base  = idx_a & ~1u;
            const float4 f4 = *(const float4*)(tab + 2u * base);
            const bool hi = (idx_a & 1u) != 0u;
            cva[q] = hi ? make_float2(f4.z, f4.w) : make_float2(f4.x, f4.y);
            cvb[q] = hi ? make_float2(f4.x, f4.y) : make_float2(f4.z, f4.w);
        }
    } else {
        const uint32_t hx0 = cx, hx1 = cx + 1u;
        #pragma unroll
        for (int q = 0; q < 4; ++q) {
            const uint32_t idx_a = (hx0 ^ hyz[q]) & (TABLE_SIZE - 1u);
            const uint32_t idx_b = (hx1 ^ hyz[q]) & (TABLE_SIZE - 1u);
            cva[q] = *(const float2*)(tab + 2u * idx_a);
            cvb[q] = *(const float2*)(tab + 2u * idx_b);
        }
    }

    float f0 = 0.0f, f1 = 0.0f;
    #pragma unroll
    for (int q = 0; q < 4; ++q) {
        const float yf = (q & 1) ? wy : wy0;
        const float zf = (q & 2) ? wz : wz0;
        const float wgt_a = (wx0 * yf) * zf;
        const float wgt_b = (wx  * yf) * zf;
        f0 = fmaf(wgt_a, cva[q].x, f0);
        f1 = fmaf(wgt_a, cva[q].y, f1);
        f0 = fmaf(wgt_b, cvb[q].x, f0);
        f1 = fmaf(wgt_b, cvb[q].y, f1);
    }

    a_ws[(size_t)(2 * l + 0) * n + p] = (_Float16)(f0 * 256.0f);
    a_ws[(size_t)(2 * l + 1) * n + p] = (_Float16)(f1 * 256.0f);
}

// ============================ MFMA MLP ============================
// Round-10 structure minus pid indirection; writes outs[] coalesced in
// sorted order (unscatter kernel reorders).
__global__ __launch_bounds__(256, 2)
void mlp_mfma_kernel(const _Float16* __restrict__ a_ws,  // [32][N] f16 x256
                     const float* __restrict__ W1,
                     const float* __restrict__ b1,
                     const float* __restrict__ W2,
                     const float* __restrict__ b2,
                     const float* __restrict__ W3,
                     const float* __restrict__ b3,
                     float* __restrict__ outs,           // [N] sorted order
                     int n)
{
    __shared__ float lds[4 * 64 * 16];

    const int lane    = threadIdx.x & 63;
    const int wave_id = threadIdx.x >> 6;
    const int m       = lane & 15;
    const int q       = lane >> 4;
    float* __restrict__ myl = &lds[wave_id * 1024];

    const float b3s = b3[0];

    v8h a1[4];
    #pragma unroll
    for (int t = 0; t < 4; ++t)
        #pragma unroll
        for (int j = 0; j < 8; ++j)
            a1[t][j] = (_Float16)W1[(8 * q + j) * 64 + 16 * t + m];

    v8h a2[2][4];
    #pragma unroll
    for (int c = 0; c < 2; ++c)
        #pragma unroll
        for (int t = 0; t < 4; ++t)
            #pragma unroll
            for (int j = 0; j < 8; ++j)
                a2[c][t][j] = (_Float16)W2[(32 * c + 8 * q + j) * 64 + 16 * t + m];

    float bias1v[16], bias2v[16], w3v[16];
    #pragma unroll
    for (int t = 0; t < 4; ++t)
        #pragma unroll
        for (int r = 0; r < 4; ++r) {
            const int ch = 16 * t + 4 * q + r;
            bias1v[4 * t + r] = 256.0f * b1[ch];
            bias2v[4 * t + r] = 256.0f * b2[ch];
            w3v[4 * t + r]    = W3[ch];
        }

    const int nt = (n + 15) >> 4;
    const int stride = gridDim.x * 4;
    const int gw = blockIdx.x * 4 + wave_id;
    if (gw >= nt) return;

    v8h bh;
    {
        const int p0 = gw * 16;
        const int pr = (p0 + m < n) ? (p0 + m) : (n - 1);
        #pragma unroll
        for (int j = 0; j < 8; ++j)
            bh[j] = a_ws[(size_t)(8 * q + j) * n + pr];
    }

    for (int tile = gw; tile < nt; tile += stride) {
        const int p0 = tile * 16;

        v8h bhn = bh;
        const int nx = tile + stride;
        if (nx < nt) {
            const int p0n = nx * 16;
            const int prn = (p0n + m < n) ? (p0n + m) : (n - 1);
            #pragma unroll
            for (int j = 0; j < 8; ++j)
                bhn[j] = a_ws[(size_t)(8 * q + j) * n + prn];
        }

        v4f acc1[4];
        #pragma unroll
        for (int t = 0; t < 4; ++t) {
            #pragma unroll
            for (int r = 0; r < 4; ++r) acc1[t][r] = bias1v[4 * t + r];
            acc1[t] = __builtin_amdgcn_mfma_f32_16x16x32_f16(a1[t], bh, acc1[t], 0, 0, 0);
        }

        #pragma unroll
        for (int t = 0; t < 4; ++t)
            #pragma unroll
            for (int r = 0; r < 4; ++r)
                myl[(16 * t + 4 * q + r) * 16 + m] = fmaxf(acc1[t][r], 0.0f);
        __threadfence_block();

        v8h b2h[2];
        #pragma unroll
        for (int c = 0; c < 2; ++c)
            #pragma unroll
            for (int j = 0; j < 8; ++j)
                b2h[c][j] = (_Float16)myl[(32 * c + 8 * q + j) * 16 + m];

        v4f acc2[4];
        #pragma unroll
        for (int t = 0; t < 4; ++t) {
            #pragma unroll
            for (int r = 0; r < 4; ++r) acc2[t][r] = bias2v[4 * t + r];
            acc2[t] = __builtin_amdgcn_mfma_f32_16x16x32_f16(a2[0][t], b2h[0], acc2[t], 0, 0, 0);
            acc2[t] = __builtin_amdgcn_mfma_f32_16x16x32_f16(a2[1][t], b2h[1], acc2[t], 0, 0, 0);
        }

        float partial = 0.0f;
        #pragma unroll
        for (int t = 0; t < 4; ++t)
            #pragma unroll
            for (int r = 0; r < 4; ++r)
                partial = fmaf(fmaxf(acc2[t][r], 0.0f), w3v[4 * t + r], partial);

        partial += __shfl_xor(partial, 16);
        partial += __shfl_xor(partial, 32);

        if (q == 0 && p0 + m < n)
            outs[p0 + m] = partial * (1.0f / 256.0f) + b3s;

        bh = bhn;
    }
}

// out[i] = outs[rank_inv[i]] : coalesced write, random 4B gather (cheap)
__global__ void unscatter_kernel(const float* __restrict__ outs,
                                 const int* __restrict__ rank_inv,
                                 float* __restrict__ out, int n) {
    const int i = blockIdx.x * blockDim.x + threadIdx.x;
    if (i < n) out[i] = outs[rank_inv[i]];
}

// ==================== Fallback: round-4 fused kernel ====================
__global__ __launch_bounds__(256, 4)
void hashgrid_mlp_fused(const float* __restrict__ x,
                        const float* __restrict__ tables,
                        const float* __restrict__ resolutions,
                        const float* __restrict__ W1,
                        const float* __restrict__ b1,
                        const float* __restrict__ W2,
                        const float* __restrict__ b2,
                        const float* __restrict__ W3,
                        const float* __restrict__ b3,
                        float* __restrict__ out,
                        int n)
{
    const int i  = blockIdx.x * blockDim.x + threadIdx.x;
    const int ip = (i < n) ? i : (n - 1);

    const float x0 = x[3 * ip + 0] * 0.5f + 0.5f;
    const float x1 = x[3 * ip + 1] * 0.5f + 0.5f;
    const float x2 = x[3 * ip + 2] * 0.5f + 0.5f;

    float h1[64];
    #pragma unroll
    for (int j = 0; j < 64; ++j) h1[j] = b1[j];

    #pragma unroll
    for (int l = 0; l < N_LEVELS; ++l) {
        const float res = resolutions[l];
        const float px = x0 * res, py = x1 * res, pz = x2 * res;
        const float fx = floorf(px), fy = floorf(py), fz = floorf(pz);
        const float wx = px - fx, wy = py - fy, wz = pz - fz;
        const uint32_t cx = (uint32_t)fx;
        const uint32_t cy = (uint32_t)fy;
        const uint32_t cz = (uint32_t)fz;
        const uint32_t hx0 = cx,           hx1 = cx + 1u;
        const uint32_t hy0 = cy * PRIME_Y, hy1 = hy0 + PRIME_Y;
        const uint32_t hz0 = cz * PRIME_Z, hz1 = hz0 + PRIME_Z;
        const float wx0 = 1.0f - wx, wy0 = 1.0f - wy, wz0 = 1.0f - wz;
        const float* __restrict__ tab = tables + (size_t)l * (size_t)TABLE_SIZE * 2u;

        float f0 = 0.0f, f1 = 0.0f;
        #pragma unroll
        for (int c = 0; c < 8; ++c) {
            const uint32_t h = ((c & 1) ? hx1 : hx0) ^
                               ((c & 2) ? hy1 : hy0) ^
                               ((c & 4) ? hz1 : hz0);
            const uint32_t idx = h & (TABLE_SIZE - 1u);
            const float2 fv = *(const float2*)(tab + 2u * idx);
            const float wgt = ((c & 1) ? wx : wx0) *
                              ((c & 2) ? wy : wy0) *
                              ((c & 4) ? wz : wz0);
            f0 = fmaf(wgt, fv.x, f0);
            f1 = fmaf(wgt, fv.y, f1);
        }
        const float* __restrict__ w1a = W1 + (2 * l + 0) * 64;
        const float* __restrict__ w1b = W1 + (2 * l + 1) * 64;
        #pragma unroll
        for (int j = 0; j < 64; ++j)
            h1[j] = fmaf(f1, w1b[j], fmaf(f0, w1a[j], h1[j]));
    }

    #pragma unroll
    for (int j = 0; j < 64; ++j) h1[j] = fmaxf(h1[j], 0.0f);

    float accum = b3[0];
    #pragma unroll
    for (int half = 0; half < 2; ++half) {
        float h2[32];
        #pragma unroll
        for (int j = 0; j < 32; ++j) h2[j] = b2[half * 32 + j];
        #pragma unroll
        for (int k = 0; k < 64; ++k) {
            const float hk = h1[k];
            const float* __restrict__ w2row = W2 + k * 64 + half * 32;
            #pragma unroll
            for (int j = 0; j < 32; ++j)
                h2[j] = fmaf(hk, w2row[j], h2[j]);
        }
        #pragma unroll
        for (int j = 0; j < 32; ++j)
            accum = fmaf(fmaxf(h2[j], 0.0f), W3[half * 32 + j], accum);
    }
    out[ip] = accum;
}

extern "C" void kernel_launch(void* const* d_in, const int* in_sizes, int n_in,
                              void* d_out, int out_size, void* d_ws, size_t ws_size,
                              hipStream_t stream) {
    const float* x           = (const float*)d_in[0];
    const float* tables      = (const float*)d_in[1];
    const float* resolutions = (const float*)d_in[2];
    const float* W1          = (const float*)d_in[3];
    const float* b1          = (const float*)d_in[4];
    const float* W2          = (const float*)d_in[5];
    const float* b2          = (const float*)d_in[6];
    const float* W3          = (const float*)d_in[7];
    const float* b3          = (const float*)d_in[8];
    float* out               = (float*)d_out;

    const int n = out_size;  // 2,000,000
    const int block = 256;
    const int grid_pts = (n + block - 1) / block;
    const int chunk = (n + SORT_B - 1) / SORT_B;

    // ---- workspace layout ----
    // a_ws (128 MB) is written only by encode, AFTER the sort finishes, so
    // the sort's metadata (g_hist 34 MB + g_part 34 MB) aliases into it.
    size_t off = 0;
    #define CARVE(bytes) (off = (off + 255) & ~(size_t)255, off += (bytes), off - (bytes))
    const size_t aws_off   = CARVE((size_t)32 * n * sizeof(_Float16)); // 128 MB
    const size_t xs_off    = CARVE((size_t)3 * n * sizeof(float));     //  24 MB
    const size_t rank_off  = CARVE((size_t)n * sizeof(int));           //   8 MB
    const size_t outs_off  = CARVE((size_t)n * sizeof(float));         //   8 MB
    const size_t tot_off   = CARVE((size_t)NB * sizeof(uint32_t));
    const size_t pref_off  = CARVE((size_t)NB * sizeof(uint32_t));
    const size_t base_off  = CARVE((size_t)NB * sizeof(uint32_t));
    const size_t bsum_off  = CARVE(1024 * sizeof(uint32_t));
    const size_t bbase_off = CARVE(1024 * sizeof(uint32_t));
    const size_t total_ws  = off;
    #undef CARVE

    if (ws_size >= total_ws) {
        char* ws = (char*)d_ws;
        _Float16* a_ws   = (_Float16*)(ws + aws_off);
        uint32_t* g_hist = (uint32_t*)(ws + aws_off);                          // alias
        uint32_t* g_part = (uint32_t*)(ws + aws_off + (size_t)SORT_B * NB * 4);// alias
        float*    xs     = (float*)(ws + xs_off);
        int*      rank   = (int*)(ws + rank_off);
        float*    outs   = (float*)(ws + outs_off);
        uint32_t* totals = (uint32_t*)(ws + tot_off);
        uint32_t* pref   = (uint32_t*)(ws + pref_off);
        uint32_t* base   = (uint32_t*)(ws + base_off);
        uint32_t* bsum   = (uint32_t*)(ws + bsum_off);
        uint32_t* bbase  = (uint32_t*)(ws + bbase_off);

        hist_kernel<<<SORT_B, block, 0, stream>>>(x, g_hist, n, chunk);
        scan_cols_kernel<<<NB / 256, block, 0, stream>>>(g_hist, g_part, totals);
        scan_block_kernel<<<NB / 256, block, 0, stream>>>(totals, pref, bsum);
        scan_top_kernel<<<1, 1024, 0, stream>>>(bsum, bbase, NB / 256);
        addback_kernel<<<NB / 256, block, 0, stream>>>(pref, bbase, base);
        scatter_kernel<<<SORT_B, block, 0, stream>>>(x, base, g_part, xs, rank, n, chunk);

        dim3 grid_enc(grid_pts, N_LEVELS);   // y = level, slow-varying
        encode_kernel<<<grid_enc, block, 0, stream>>>(xs, tables, resolutions, a_ws, n);
        mlp_mfma_kernel<<<1024, block, 0, stream>>>(a_ws, W1, b1, W2, b2, W3, b3, outs, n);
        unscatter_kernel<<<grid_pts, block, 0, stream>>>(outs, rank, out, n);
    } else {
        hashgrid_mlp_fused<<<grid_pts, block, 0, stream>>>(
            x, tables, resolutions, W1, b1, W2, b2, W3, b3, out, n);
    }
}